// Round 10
// baseline (271.941 us; speedup 1.0000x reference)
//
#include <hip/hip_runtime.h>
#include <hip/hip_cooperative_groups.h>

namespace cg = cooperative_groups;

#define CUTOFF 5.0f
#define CUTOFF2 25.0f
#define GAMMA 40.96f              // (32/5)^2
#define MU_STEP 0.16129032f       // 5/31
#define INV_MU 6.2f               // 31/5
#define PI_F 3.14159265358979f
#define MAXDEG 64                 // Poisson(4.42): P(deg>=25) ~ 1e-12

// ---------------------------------------------------------------------------
// R10: single cooperative kernel = zero-deg | grid.sync | bucket-fill |
// grid.sync | gather+finalize. R9 ledger bounded fill+overheads at ~85 us of
// 149 total vs gather 61; fusing removes 2 dispatch boundaries + memset
// dispatch and directly measures fill's true cost. Phase logic = R9 verbatim
// (fill predicate d2<25 == sqrt<5, monotone).
// ---------------------------------------------------------------------------
__global__ __launch_bounds__(256) void k_fused(
    const float* __restrict__ h, const float* __restrict__ pos,
    const int* __restrict__ ei, const float* __restrict__ Wrbf,
    const float* __restrict__ Wout, const float* __restrict__ Wsgp,
    float* __restrict__ out, int* __restrict__ deg, int* __restrict__ rec,
    int N, int E, int tiles)
{
    cg::grid_group grid = cg::this_grid();

    __shared__ float s_wr[512];        // W_rbf [32,16]
    __shared__ float s_Wout[256];
    __shared__ float s_Wsgp[256];
    __shared__ float s_agg[16*132];
    __shared__ float s_h[16*132];

    const int t     = threadIdx.x;
    const int nl    = t >> 4;
    const int c     = t & 15;
    const int lane  = t & 63;
    const int gbase = lane & 48;       // channel-group base within wave
    const int gstride = gridDim.x * 256;

    // stage constant weights (first use is after two grid.syncs + a barrier)
    s_wr[t]       = Wrbf[t];
    s_wr[t + 256] = Wrbf[t + 256];
    s_Wout[t] = Wout[t];
    s_Wsgp[t] = Wsgp[t];

    // ---- phase A: zero deg ----
    for (int i = blockIdx.x * 256 + t; i < N; i += gstride) deg[i] = 0;
    grid.sync();

    // ---- phase B: bucket fill ----
    for (int e = blockIdx.x * 256 + t; e < E; e += gstride) {
        int src = ei[e], dst = ei[E + e];
        float dx = pos[dst*3+0] - pos[src*3+0];
        float dy = pos[dst*3+1] - pos[src*3+1];
        float dz = pos[dst*3+2] - pos[src*3+2];
        float d2 = dx*dx + dy*dy + dz*dz;
        if (d2 < CUTOFF2) {
            int slot = atomicAdd(&deg[dst], 1);
            if (slot < MAXDEG) rec[dst*MAXDEG + slot] = src;
        }
    }
    grid.sync();

    // ---- phase C: gather + finalize, grid-stride over 16-node tiles ----
    for (int tile = blockIdx.x; tile < tiles; tile += gridDim.x) {
        const long long nodeBase = (long long)tile * 16;
        const long long n = nodeBase + nl;

        for (int idx = t; idx < 512; idx += 256) {
            int nn = idx >> 5;
            int r  = idx & 31;
            long long node = nodeBase + nn;
            float4 vh = make_float4(0,0,0,0);
            if (node < N) vh = *(const float4*)(h + node*128 + (long long)r*4);
            *(float4*)(&s_h[nn*132 + r*4]) = vh;
        }
        __syncthreads();

        float m0=0,m1=0,m2=0,m3=0,m4=0,m5=0,m6=0,m7=0;
        if (n < N) {
            const float px = pos[n*3+0], py = pos[n*3+1], pz = pos[n*3+2];
            const int start = (int)n * MAXDEG;
            const int dg    = min(deg[n], MAXDEG);
            for (int base = 0; base < dg; base += 2) {
                const int i1ok = (base + 1 < dg) ? 1 : 0;
                const int s0 = rec[start + base];
                const int s1 = rec[start + base + i1ok];

                const float4* hp0 = (const float4*)(h + (((long long)s0*16 + c) << 3));
                const float4* hp1 = (const float4*)(h + (((long long)s1*16 + c) << 3));
                const float4 A0 = hp0[0], B0 = hp0[1];
                const float4 A1 = hp1[0], B1 = hp1[1];

                const float dx0 = px - pos[s0*3+0];
                const float dy0 = py - pos[s0*3+1];
                const float dz0 = pz - pos[s0*3+2];
                const float dx1 = px - pos[s1*3+0];
                const float dy1 = py - pos[s1*3+1];
                const float dz1 = pz - pos[s1*3+2];

                const float d0 = sqrtf(dx0*dx0 + dy0*dy0 + dz0*dz0 + 1e-12f);
                const float d1 = sqrtf(dx1*dx1 + dy1*dy1 + dz1*dz1 + 1e-12f);
                const float inv0 = 1.0f / d0, inv1 = 1.0f / d1;
                const float ux0 = dx0*inv0, uy0 = dy0*inv0, uz0 = dz0*inv0;
                const float ux1 = dx1*inv1, uy1 = dy1*inv1, uz1 = dz1*inv1;
                const float env0 = 0.5f * (__cosf(PI_F * d0 * (1.0f/CUTOFF)) + 1.0f);
                const float env1 = 0.5f * (__cosf(PI_F * d1 * (1.0f/CUTOFF)) + 1.0f);

                // 7-term RBF window clamped into [0,31]; cooperative exp:
                // lanes 0-7 of the channel group cover edge0, 8-15 edge1.
                const int kl0 = min(max(0, __float2int_rn(d0 * INV_MU) - 3), 25);
                const int kl1 = min(max(0, __float2int_rn(d1 * INV_MU) - 3), 25);
                const int   sel   = c >> 3;
                const float dsel  = sel ? d1 : d0;
                const int   klsel = sel ? kl1 : kl0;
                const float xx = dsel - MU_STEP * (float)(klsel + (c & 7));
                const float ee = __expf(-GAMMA * xx * xx);

                float w0 = 0.0f, w1 = 0.0f;
                #pragma unroll
                for (int j = 0; j < 7; ++j) {
                    const float e0 = __shfl(ee, gbase + j);
                    const float e1 = __shfl(ee, gbase + 8 + j);
                    w0 += e0 * s_wr[(kl0 + j)*16 + c];
                    w1 += e1 * s_wr[(kl1 + j)*16 + c];
                }
                w0 *= env0;
                w1 *= env1 * (float)i1ok;

                // gp(a,u), u grade-1; blades: 0:1 1:e1 2:e2 3:e3 4:e12 5:e13 6:e23 7:e123
                m0 += (A0.y*ux0 + A0.z*uy0 + A0.w*uz0) * w0 + (A1.y*ux1 + A1.z*uy1 + A1.w*uz1) * w1;
                m1 += (A0.x*ux0 + B0.x*uy0 + B0.y*uz0) * w0 + (A1.x*ux1 + B1.x*uy1 + B1.y*uz1) * w1;
                m2 += (A0.x*uy0 - B0.x*ux0 + B0.z*uz0) * w0 + (A1.x*uy1 - B1.x*ux1 + B1.z*uz1) * w1;
                m3 += (A0.x*uz0 - B0.y*ux0 - B0.z*uy0) * w0 + (A1.x*uz1 - B1.y*ux1 - B1.z*uy1) * w1;
                m4 += (A0.y*uy0 - A0.z*ux0 + B0.w*uz0) * w0 + (A1.y*uy1 - A1.z*ux1 + B1.w*uz1) * w1;
                m5 += (A0.y*uz0 - A0.w*ux0 - B0.w*uy0) * w0 + (A1.y*uz1 - A1.w*ux1 - B1.w*uy1) * w1;
                m6 += (A0.z*uz0 - A0.w*uy0 + B0.w*ux0) * w0 + (A1.z*uz1 - A1.w*uy1 + B1.w*ux1) * w1;
                m7 += (B0.z*ux0 - B0.y*uy0 + B0.x*uz0) * w0 + (B1.z*ux1 - B1.y*uy1 + B1.x*uz1) * w1;
            }
        }

        float* ag = &s_agg[nl*132 + c*8];
        *(float4*)(ag)     = make_float4(m0, m1, m2, m3);
        *(float4*)(ag + 4) = make_float4(m4, m5, m6, m7);
        __syncthreads();

        const int o = c;
        const float* A = &s_agg[nl*132];
        const float* H = &s_h[nl*132];

        float o0=0,o1=0,o2=0,o3=0,o4=0,o5=0,o6=0,o7=0;
        float q0=0,q1=0,q2=0,q3=0,q4=0,q5=0,q6=0,q7=0;
        #pragma unroll
        for (int cc = 0; cc < 16; ++cc) {
            const float wo = s_Wout[cc*16 + o];
            const float ws = s_Wsgp[cc*16 + o];
            const float* a  = A + cc*8;
            const float* hh = H + cc*8;
            o0 += a[0]*wo; o1 += a[1]*wo; o2 += a[2]*wo; o3 += a[3]*wo;
            o4 += a[4]*wo; o5 += a[5]*wo; o6 += a[6]*wo; o7 += a[7]*wo;
            q0 += hh[0]*ws; q1 += hh[1]*ws; q2 += hh[2]*ws; q3 += hh[3]*ws;
            q4 += hh[4]*ws; q5 += hh[5]*ws; q6 += hh[6]*ws; q7 += hh[7]*ws;
        }

        // res = out + gp(out, q), full Cl(3,0) Cayley product
        const float r0 = o0 + (o0*q0 + o1*q1 + o2*q2 + o3*q3 - o4*q4 - o5*q5 - o6*q6 - o7*q7);
        const float r1 = o1 + (o0*q1 + o1*q0 - o2*q4 - o3*q5 + o4*q2 + o5*q3 - o6*q7 - o7*q6);
        const float r2 = o2 + (o0*q2 + o1*q4 + o2*q0 - o3*q6 - o4*q1 + o5*q7 + o6*q3 + o7*q5);
        const float r3 = o3 + (o0*q3 + o1*q5 + o2*q6 + o3*q0 - o4*q7 - o5*q1 - o6*q2 - o7*q4);
        const float r4 = o4 + (o0*q4 + o1*q2 - o2*q1 + o3*q7 + o4*q0 - o5*q6 + o6*q5 + o7*q3);
        const float r5 = o5 + (o0*q5 + o1*q3 - o2*q7 - o3*q1 + o4*q6 + o5*q0 - o6*q4 - o7*q2);
        const float r6 = o6 + (o0*q6 + o1*q7 + o2*q3 - o3*q2 - o4*q5 + o5*q4 + o6*q0 + o7*q1);
        const float r7 = o7 + (o0*q7 + o1*q6 - o2*q5 + o3*q4 + o4*q3 - o5*q2 + o6*q1 + o7*q0);

        if (n < N) {
            float* op = out + (n*16 + o)*8;
            *(float4*)(op)     = make_float4(r0, r1, r2, r3);
            *(float4*)(op + 4) = make_float4(r4, r5, r6, r7);
        }
        __syncthreads();   // protect s_h/s_agg before next tile's staging
    }
}

extern "C" void kernel_launch(void* const* d_in, const int* in_sizes, int n_in,
                              void* d_out, int out_size, void* d_ws, size_t ws_size,
                              hipStream_t stream) {
    const float* h    = (const float*)d_in[0];   // [N,16,8]
    const float* pos  = (const float*)d_in[1];   // [N,3]
    const int*   ei   = (const int*)d_in[2];     // [2,E]
    const float* Wrbf = (const float*)d_in[3];   // [32,16]
    const float* Wout = (const float*)d_in[4];   // [16,16]
    const float* Wsgp = (const float*)d_in[5];   // [16,16]
    float* out = (float*)d_out;

    int N = in_sizes[0] / 128;
    int E = in_sizes[2] / 2;
    int tiles = (N + 15) / 16;

    // ws layout (ints): deg[N] | rec[N*MAXDEG]  (~13 MB)
    int* deg = (int*)d_ws;
    int* rec = deg + N;

    // co-resident grid: occupancy query (LDS 20992 B -> expect 7 blocks/CU)
    int blocksPerCU = 0;
    hipOccupancyMaxActiveBlocksPerMultiprocessor(&blocksPerCU, k_fused, 256, 0);
    if (blocksPerCU < 1) blocksPerCU = 1;
    int grid = blocksPerCU * 256;          // 256 CUs on MI355X

    void* args[] = { (void*)&h, (void*)&pos, (void*)&ei, (void*)&Wrbf,
                     (void*)&Wout, (void*)&Wsgp, (void*)&out,
                     (void*)&deg, (void*)&rec, (void*)&N, (void*)&E, (void*)&tiles };
    hipLaunchCooperativeKernel((const void*)k_fused, dim3(grid), dim3(256),
                               args, 0, stream);
}

// Round 11
// 161.259 us; speedup vs baseline: 1.6864x; 1.6864x over previous
//
#include <hip/hip_runtime.h>

#define CUTOFF 5.0f
#define CUTOFF2 25.0f
#define GAMMA 40.96f              // (32/5)^2
#define MU_STEP 0.16129032f       // 5/31
#define INV_MU 6.2f               // 31/5
#define PI_F 3.14159265358979f
#define MAXDEG 64                 // Poisson(4.42): P(deg>=25) ~ 1e-12

// ---------------------------------------------------------------------------
// R11 = R9 structure (3 dispatches: memset | bucket-fill | gather+finalize;
// R10 proved cooperative fusion regresses via occupancy collapse) + gather
// unrolled to 4 edges/iter: 4 independent h/pos load chains (MLP x2 vs R8),
// cooperative RBF exp in two rounds. Gather is latency-bound at ~20% per-wave
// duty (R9: VALUBusy 48% at ~2.75 waves/SIMD); more per-wave MLP is the lever.
// ---------------------------------------------------------------------------

__global__ __launch_bounds__(256) void k_fill_direct(
    const float* __restrict__ pos, const int* __restrict__ ei,
    int* __restrict__ deg, int* __restrict__ rec, int E)
{
    int e = blockIdx.x * 256 + threadIdx.x;
    if (e >= E) return;
    int src = ei[e], dst = ei[E + e];
    float dx = pos[dst*3+0] - pos[src*3+0];
    float dy = pos[dst*3+1] - pos[src*3+1];
    float dz = pos[dst*3+2] - pos[src*3+2];
    float d2 = dx*dx + dy*dy + dz*dz;
    if (d2 < CUTOFF2) {                       // == (sqrt(d2+1e-12) < 5), monotone
        int slot = atomicAdd(&deg[dst], 1);
        if (slot < MAXDEG) rec[dst*MAXDEG + slot] = src;
    }
}

__device__ __forceinline__ void gp_acc(
    const float4& A, const float4& B, float ux, float uy, float uz, float w,
    float& m0, float& m1, float& m2, float& m3,
    float& m4, float& m5, float& m6, float& m7)
{
    // gp(a,u), u grade-1; blades: 0:1 1:e1 2:e2 3:e3 4:e12 5:e13 6:e23 7:e123
    m0 += (A.y*ux + A.z*uy + A.w*uz) * w;
    m1 += (A.x*ux + B.x*uy + B.y*uz) * w;
    m2 += (A.x*uy - B.x*ux + B.z*uz) * w;
    m3 += (A.x*uz - B.y*ux - B.z*uy) * w;
    m4 += (A.y*uy - A.z*ux + B.w*uz) * w;
    m5 += (A.y*uz - A.w*ux - B.w*uy) * w;
    m6 += (A.z*uz - A.w*uy + B.w*ux) * w;
    m7 += (B.z*ux - B.y*uy + B.x*uz) * w;
}

// Gather + finalize: 16 nodes/block, thread (nl,c) owns channel c of node nl.
// 4 edges per iteration; the 16 lanes of a channel group cooperatively
// compute RBF exps in two rounds (lanes 0-7 edge0/2, lanes 8-15 edge1/3).
__global__ __launch_bounds__(256) void k_gather_finalize(
    const float* __restrict__ h, const float* __restrict__ pos,
    const int* __restrict__ rec, const int* __restrict__ deg,
    const float* __restrict__ Wrbf, const float* __restrict__ Wout,
    const float* __restrict__ Wsgp, float* __restrict__ out, int N)
{
    __shared__ float s_wr[512];        // W_rbf [32,16]
    __shared__ float s_Wout[256];
    __shared__ float s_Wsgp[256];
    __shared__ float s_agg[16*132];
    __shared__ float s_h[16*132];

    const int t  = threadIdx.x;
    const int nl = t >> 4;
    const int c  = t & 15;
    const int lane  = t & 63;
    const int gbase = lane & 48;       // channel-group base within wave
    const long long nodeBase = (long long)blockIdx.x * 16;
    const long long n = nodeBase + nl;

    s_wr[t]       = Wrbf[t];
    s_wr[t + 256] = Wrbf[t + 256];
    s_Wout[t] = Wout[t];
    s_Wsgp[t] = Wsgp[t];

    for (int idx = t; idx < 512; idx += 256) {
        int nn = idx >> 5;
        int r  = idx & 31;
        long long node = nodeBase + nn;
        float4 vh = make_float4(0,0,0,0);
        if (node < N) vh = *(const float4*)(h + node*128 + (long long)r*4);
        *(float4*)(&s_h[nn*132 + r*4]) = vh;
    }
    __syncthreads();

    float m0=0,m1=0,m2=0,m3=0,m4=0,m5=0,m6=0,m7=0;
    if (n < N) {
        const float px = pos[n*3+0], py = pos[n*3+1], pz = pos[n*3+2];
        const int start = (int)n * MAXDEG;
        const int dg    = min(deg[n], MAXDEG);
        const int dgm1  = dg - 1;
        for (int base = 0; base < dg; base += 4) {
            const int i1 = min(base + 1, dgm1);
            const int i2 = min(base + 2, dgm1);
            const int i3 = min(base + 3, dgm1);
            const float v1 = (base + 1 < dg) ? 1.0f : 0.0f;
            const float v2 = (base + 2 < dg) ? 1.0f : 0.0f;
            const float v3 = (base + 3 < dg) ? 1.0f : 0.0f;
            const int s0 = rec[start + base];
            const int s1 = rec[start + i1];
            const int s2 = rec[start + i2];
            const int s3 = rec[start + i3];

            // 4 independent 32B h chains in flight during the math
            const float4* hp0 = (const float4*)(h + (((long long)s0*16 + c) << 3));
            const float4* hp1 = (const float4*)(h + (((long long)s1*16 + c) << 3));
            const float4* hp2 = (const float4*)(h + (((long long)s2*16 + c) << 3));
            const float4* hp3 = (const float4*)(h + (((long long)s3*16 + c) << 3));
            const float4 A0 = hp0[0], B0 = hp0[1];
            const float4 A1 = hp1[0], B1 = hp1[1];
            const float4 A2 = hp2[0], B2 = hp2[1];
            const float4 A3 = hp3[0], B3 = hp3[1];

            const float dx0 = px - pos[s0*3+0], dy0 = py - pos[s0*3+1], dz0 = pz - pos[s0*3+2];
            const float dx1 = px - pos[s1*3+0], dy1 = py - pos[s1*3+1], dz1 = pz - pos[s1*3+2];
            const float dx2 = px - pos[s2*3+0], dy2 = py - pos[s2*3+1], dz2 = pz - pos[s2*3+2];
            const float dx3 = px - pos[s3*3+0], dy3 = py - pos[s3*3+1], dz3 = pz - pos[s3*3+2];

            const float d0 = sqrtf(dx0*dx0 + dy0*dy0 + dz0*dz0 + 1e-12f);
            const float d1 = sqrtf(dx1*dx1 + dy1*dy1 + dz1*dz1 + 1e-12f);
            const float d2 = sqrtf(dx2*dx2 + dy2*dy2 + dz2*dz2 + 1e-12f);
            const float d3 = sqrtf(dx3*dx3 + dy3*dy3 + dz3*dz3 + 1e-12f);
            const float in0 = 1.0f/d0, in1 = 1.0f/d1, in2 = 1.0f/d2, in3 = 1.0f/d3;
            const float ux0 = dx0*in0, uy0 = dy0*in0, uz0 = dz0*in0;
            const float ux1 = dx1*in1, uy1 = dy1*in1, uz1 = dz1*in1;
            const float ux2 = dx2*in2, uy2 = dy2*in2, uz2 = dz2*in2;
            const float ux3 = dx3*in3, uy3 = dy3*in3, uz3 = dz3*in3;
            const float env0 = 0.5f * (__cosf(PI_F * d0 * (1.0f/CUTOFF)) + 1.0f);
            const float env1 = 0.5f * (__cosf(PI_F * d1 * (1.0f/CUTOFF)) + 1.0f);
            const float env2 = 0.5f * (__cosf(PI_F * d2 * (1.0f/CUTOFF)) + 1.0f);
            const float env3 = 0.5f * (__cosf(PI_F * d3 * (1.0f/CUTOFF)) + 1.0f);

            // 7-term RBF windows clamped into [0,31] (dropped terms < 4e-8)
            const int kl0 = min(max(0, __float2int_rn(d0 * INV_MU) - 3), 25);
            const int kl1 = min(max(0, __float2int_rn(d1 * INV_MU) - 3), 25);
            const int kl2 = min(max(0, __float2int_rn(d2 * INV_MU) - 3), 25);
            const int kl3 = min(max(0, __float2int_rn(d3 * INV_MU) - 3), 25);

            // cooperative exp, two rounds: A covers edges 0/1, B covers 2/3
            const int   sel = c >> 3;
            const float dA  = sel ? d1 : d0;   const int klA = sel ? kl1 : kl0;
            const float dB  = sel ? d3 : d2;   const int klB = sel ? kl3 : kl2;
            const float xA = dA - MU_STEP * (float)(klA + (c & 7));
            const float xB = dB - MU_STEP * (float)(klB + (c & 7));
            const float eeA = __expf(-GAMMA * xA * xA);
            const float eeB = __expf(-GAMMA * xB * xB);

            float w0 = 0.0f, w1 = 0.0f, w2 = 0.0f, w3 = 0.0f;
            #pragma unroll
            for (int j = 0; j < 7; ++j) {
                w0 += __shfl(eeA, gbase + j)     * s_wr[(kl0 + j)*16 + c];
                w1 += __shfl(eeA, gbase + 8 + j) * s_wr[(kl1 + j)*16 + c];
                w2 += __shfl(eeB, gbase + j)     * s_wr[(kl2 + j)*16 + c];
                w3 += __shfl(eeB, gbase + 8 + j) * s_wr[(kl3 + j)*16 + c];
            }
            w0 *= env0;
            w1 *= env1 * v1;
            w2 *= env2 * v2;
            w3 *= env3 * v3;

            gp_acc(A0, B0, ux0, uy0, uz0, w0, m0,m1,m2,m3,m4,m5,m6,m7);
            gp_acc(A1, B1, ux1, uy1, uz1, w1, m0,m1,m2,m3,m4,m5,m6,m7);
            gp_acc(A2, B2, ux2, uy2, uz2, w2, m0,m1,m2,m3,m4,m5,m6,m7);
            gp_acc(A3, B3, ux3, uy3, uz3, w3, m0,m1,m2,m3,m4,m5,m6,m7);
        }
    }

    __syncthreads();
    float* ag = &s_agg[nl*132 + c*8];
    *(float4*)(ag)     = make_float4(m0, m1, m2, m3);
    *(float4*)(ag + 4) = make_float4(m4, m5, m6, m7);
    __syncthreads();

    const int o = c;
    const float* A = &s_agg[nl*132];
    const float* H = &s_h[nl*132];

    float o0=0,o1=0,o2=0,o3=0,o4=0,o5=0,o6=0,o7=0;
    float q0=0,q1=0,q2=0,q3=0,q4=0,q5=0,q6=0,q7=0;
    #pragma unroll
    for (int cc = 0; cc < 16; ++cc) {
        const float wo = s_Wout[cc*16 + o];
        const float ws = s_Wsgp[cc*16 + o];
        const float* a  = A + cc*8;
        const float* hh = H + cc*8;
        o0 += a[0]*wo; o1 += a[1]*wo; o2 += a[2]*wo; o3 += a[3]*wo;
        o4 += a[4]*wo; o5 += a[5]*wo; o6 += a[6]*wo; o7 += a[7]*wo;
        q0 += hh[0]*ws; q1 += hh[1]*ws; q2 += hh[2]*ws; q3 += hh[3]*ws;
        q4 += hh[4]*ws; q5 += hh[5]*ws; q6 += hh[6]*ws; q7 += hh[7]*ws;
    }

    // res = out + gp(out, q), full Cl(3,0) Cayley product
    const float r0 = o0 + (o0*q0 + o1*q1 + o2*q2 + o3*q3 - o4*q4 - o5*q5 - o6*q6 - o7*q7);
    const float r1 = o1 + (o0*q1 + o1*q0 - o2*q4 - o3*q5 + o4*q2 + o5*q3 - o6*q7 - o7*q6);
    const float r2 = o2 + (o0*q2 + o1*q4 + o2*q0 - o3*q6 - o4*q1 + o5*q7 + o6*q3 + o7*q5);
    const float r3 = o3 + (o0*q3 + o1*q5 + o2*q6 + o3*q0 - o4*q7 - o5*q1 - o6*q2 - o7*q4);
    const float r4 = o4 + (o0*q4 + o1*q2 - o2*q1 + o3*q7 + o4*q0 - o5*q6 + o6*q5 + o7*q3);
    const float r5 = o5 + (o0*q5 + o1*q3 - o2*q7 - o3*q1 + o4*q6 + o5*q0 - o6*q4 - o7*q2);
    const float r6 = o6 + (o0*q6 + o1*q7 + o2*q3 - o3*q2 - o4*q5 + o5*q4 + o6*q0 + o7*q1);
    const float r7 = o7 + (o0*q7 + o1*q6 - o2*q5 + o3*q4 + o4*q3 - o5*q2 + o6*q1 + o7*q0);

    if (n < N) {
        float* op = out + (n*16 + o)*8;
        *(float4*)(op)     = make_float4(r0, r1, r2, r3);
        *(float4*)(op + 4) = make_float4(r4, r5, r6, r7);
    }
}

extern "C" void kernel_launch(void* const* d_in, const int* in_sizes, int n_in,
                              void* d_out, int out_size, void* d_ws, size_t ws_size,
                              hipStream_t stream) {
    const float* h    = (const float*)d_in[0];   // [N,16,8]
    const float* pos  = (const float*)d_in[1];   // [N,3]
    const int*   ei   = (const int*)d_in[2];     // [2,E]
    const float* Wrbf = (const float*)d_in[3];   // [32,16]
    const float* Wout = (const float*)d_in[4];   // [16,16]
    const float* Wsgp = (const float*)d_in[5];   // [16,16]
    float* out = (float*)d_out;

    const int N = in_sizes[0] / 128;
    const int E = in_sizes[2] / 2;

    // ws layout (ints): deg[N] | rec[N*MAXDEG]  (~13 MB)
    int* deg = (int*)d_ws;
    int* rec = deg + N;

    hipMemsetAsync(deg, 0, (size_t)N * sizeof(int), stream);

    const int eBlocks = (E + 255) / 256;
    k_fill_direct<<<eBlocks, 256, 0, stream>>>(pos, ei, deg, rec, E);

    const int gBlocks = (N + 15) / 16;
    k_gather_finalize<<<gBlocks, 256, 0, stream>>>(
        h, pos, rec, deg, Wrbf, Wout, Wsgp, out, N);
}